// Round 1
// baseline (94.836 us; speedup 1.0000x reference)
//
#include <hip/hip_runtime.h>
#include <hip/hip_bf16.h>
#include <cstdint>
#include <cstddef>

// RBF Gram matrix: K[i,j] = exp(-gamma * max(||a_i||^2 + ||b_j||^2 - 2 a_i.b_j, 0))
// A: [8192,256] f32, B: [8192,256] f32, Out: [8192,8192] f32.
// Strategy: prepass computes f32 row norms + bf16 copies of A/B into d_ws;
// main kernel is an m97-style 128x128 bf16 MFMA GEMM with RBF epilogue.

#define GAMMA_F 0.00390625f

typedef __attribute__((ext_vector_type(8))) short short8;   // 8 bf16 (4 VGPRs)
typedef __attribute__((ext_vector_type(4))) float f32x4;    // MFMA acc

constexpr int KD = 256;    // inner dim
constexpr int ND = 8192;   // rows of A and of B (= output dims)
constexpr int BM = 128, BN = 128, BK = 32;

// f32 -> bf16 round-to-nearest-even (no NaN handling needed: inputs are normals)
__device__ __forceinline__ unsigned short f2b(float f) {
  unsigned int u = __float_as_uint(f);
  u += 0x7FFFu + ((u >> 16) & 1u);
  return (unsigned short)(u >> 16);
}

__device__ __forceinline__ void gload_lds16(const void* g, void* l) {
  __builtin_amdgcn_global_load_lds(
      (const __attribute__((address_space(1))) unsigned int*)g,
      (__attribute__((address_space(3))) unsigned int*)l, 16, 0, 0);
}

// ---------------------------------------------------------------------------
// Prepass: row L2-norms (f32, from original f32 data) + optional bf16 convert.
// One wave per row, 4 rows per 256-thread block. 16384 rows total.
// ---------------------------------------------------------------------------
__global__ __launch_bounds__(256) void norm_convert_kernel(
    const float* __restrict__ A, const float* __restrict__ B,
    unsigned short* Abf, unsigned short* Bbf,
    float* __restrict__ asq, float* __restrict__ bsq)
{
  const int lane = threadIdx.x & 63;
  const int row = blockIdx.x * 4 + (threadIdx.x >> 6);
  const float* src = A;
  unsigned short* dst = Abf;
  float* nrm = asq;
  int r = row;
  if (row >= ND) { src = B; dst = Bbf; nrm = bsq; r = row - ND; }

  const float4 v = *(const float4*)(src + (size_t)r * KD + lane * 4);
  float s = v.x * v.x + v.y * v.y + v.z * v.z + v.w * v.w;
  #pragma unroll
  for (int off = 32; off >= 1; off >>= 1) s += __shfl_xor(s, off, 64);

  if (dst) {
    const unsigned int p0 = (unsigned)f2b(v.x) | ((unsigned)f2b(v.y) << 16);
    const unsigned int p1 = (unsigned)f2b(v.z) | ((unsigned)f2b(v.w) << 16);
    *(uint2*)(dst + (size_t)r * KD + lane * 4) = make_uint2(p0, p1);
  }
  if (lane == 0) nrm[r] = s;
}

// ---------------------------------------------------------------------------
// Main GEMM + RBF epilogue.
// 256 threads = 4 waves in a 2x2 grid; each wave owns a 64x64 output sub-tile
// (4x4 fragments of 16x16, acc[4][4] f32x4). BK=32 -> 8 K-steps.
//
// LDS: A-tile [128][32] bf16 (8 KiB) at 0, B-tile at 8192. Linear destination
// for global_load_lds; data is permuted on the GLOBAL-SOURCE side by the
// involution  f(b) = b ^ (((b>>7)&3)<<4)  (flips byte-addr bits 4-5 based on
// bits 7-8, i.e. row>>1), and ds_read applies the same XOR. This spreads the
// 16-lane fragment-read groups across all eight 16B slots of the 32 banks
// (2 lanes/bank = free) instead of the 8-way conflict of the linear layout.
// ---------------------------------------------------------------------------
template <bool BF16WS>
__global__ __launch_bounds__(256) void rbf_gemm_kernel(
    const void* __restrict__ Aop, const void* __restrict__ Bop,
    const float* __restrict__ asq, const float* __restrict__ bsq,
    float* __restrict__ C)
{
  __shared__ __align__(16) char smem[16384];
  const int t = threadIdx.x;
  const int lane = t & 63;
  const int wid = t >> 6;
  const int wm = wid >> 1, wn = wid & 1;

  // XCD-aware bijective swizzle: 4096 blocks, 8 XCDs, 512 consecutive
  // tiles per XCD => each XCD's 4MB L2 holds the whole bf16 B panel.
  const int bid = blockIdx.x;
  const int wgid = ((bid & 7) << 9) | (bid >> 3);
  const int brow = (wgid >> 6) << 7;   // * BM
  const int bcol = (wgid & 63) << 7;   // * BN

  // Staging coords for thread t: dest byte (per half h) b = h*4096 + t*16.
  // Source linear offset = f(b): row unchanged (= h*64 + t/4), swizzled col.
  const int srow = t >> 2;                                    // 0..63
  const int scolb = (((t & 3) ^ ((t >> 3) & 3)) << 4);        // swizzled col byte

  // Fragment ds_read offsets (kt-invariant; single LDS buffer).
  int aoff[4], boff[4];
  #pragma unroll
  for (int f = 0; f < 4; ++f) {
    const int ra = wm * 64 + f * 16 + (lane & 15);
    aoff[f] = ra * 64 + (((lane >> 4) * 16) ^ (((ra >> 1) & 3) << 4));
    const int rb = wn * 64 + f * 16 + (lane & 15);
    boff[f] = 8192 + rb * 64 + (((lane >> 4) * 16) ^ (((rb >> 1) & 3) << 4));
  }

  f32x4 acc[4][4] = {};

  for (int kt = 0; kt < KD / BK; ++kt) {
    // ---- stage tiles ----
    if constexpr (BF16WS) {
      const char* Ab = (const char*)Aop;
      const char* Bb = (const char*)Bop;
      #pragma unroll
      for (int h = 0; h < 2; ++h) {
        gload_lds16(Ab + (size_t)(brow + h * 64 + srow) * (KD * 2) + kt * (BK * 2) + scolb,
                    smem + h * 4096 + wid * 1024);
        gload_lds16(Bb + (size_t)(bcol + h * 64 + srow) * (KD * 2) + kt * (BK * 2) + scolb,
                    smem + 8192 + h * 4096 + wid * 1024);
      }
    } else {
      // Fallback: reg-stage f32 -> bf16 inline (no big workspace needed).
      const float* Af = (const float*)Aop;
      const float* Bf = (const float*)Bop;
      #pragma unroll
      for (int h = 0; h < 2; ++h) {
        const float* sa = Af + (size_t)(brow + h * 64 + srow) * KD + kt * BK + (scolb >> 1);
        const float4 a0 = *(const float4*)sa;
        const float4 a1 = *(const float4*)(sa + 4);
        const uint4 pa = make_uint4(
            (unsigned)f2b(a0.x) | ((unsigned)f2b(a0.y) << 16),
            (unsigned)f2b(a0.z) | ((unsigned)f2b(a0.w) << 16),
            (unsigned)f2b(a1.x) | ((unsigned)f2b(a1.y) << 16),
            (unsigned)f2b(a1.z) | ((unsigned)f2b(a1.w) << 16));
        *(uint4*)(smem + h * 4096 + t * 16) = pa;
        const float* sb = Bf + (size_t)(bcol + h * 64 + srow) * KD + kt * BK + (scolb >> 1);
        const float4 b0 = *(const float4*)sb;
        const float4 b1 = *(const float4*)(sb + 4);
        const uint4 pb = make_uint4(
            (unsigned)f2b(b0.x) | ((unsigned)f2b(b0.y) << 16),
            (unsigned)f2b(b0.z) | ((unsigned)f2b(b0.w) << 16),
            (unsigned)f2b(b1.x) | ((unsigned)f2b(b1.y) << 16),
            (unsigned)f2b(b1.z) | ((unsigned)f2b(b1.w) << 16));
        *(uint4*)(smem + 8192 + h * 4096 + t * 16) = pb;
      }
    }
    __syncthreads();   // compiler drains vmcnt/lgkmcnt before s_barrier

    // ---- compute ----
    short8 af[4], bfv[4];
    #pragma unroll
    for (int f = 0; f < 4; ++f) {
      af[f]  = *(const short8*)(smem + aoff[f]);
      bfv[f] = *(const short8*)(smem + boff[f]);
    }
    #pragma unroll
    for (int fm = 0; fm < 4; ++fm)
      #pragma unroll
      for (int fn = 0; fn < 4; ++fn)
        acc[fm][fn] = __builtin_amdgcn_mfma_f32_16x16x32_bf16(
            af[fm], bfv[fn], acc[fm][fn], 0, 0, 0);
    __syncthreads();   // all reads done before next stage overwrites LDS
  }

  // ---- epilogue: K = exp2( (asq+bsq-2*dot) * (-gamma*log2e) ) ----
  // C/D layout (m89): col = lane&15, row = (lane>>4)*4 + reg.
  const float cexp = -GAMMA_F * 1.44269504088896340736f;
  float bn[4];
  int jj[4];
  #pragma unroll
  for (int fn = 0; fn < 4; ++fn) {
    jj[fn] = bcol + wn * 64 + fn * 16 + (lane & 15);
    bn[fn] = bsq[jj[fn]];
  }
  #pragma unroll
  for (int fm = 0; fm < 4; ++fm) {
    const int ib = brow + wm * 64 + fm * 16 + ((lane >> 4) << 2);
    #pragma unroll
    for (int r = 0; r < 4; ++r) {
      const float an = asq[ib + r];
      float* crow = C + (size_t)(ib + r) * ND;
      #pragma unroll
      for (int fn = 0; fn < 4; ++fn) {
        float d = an + bn[fn] - 2.0f * acc[fm][fn][r];
        d = fmaxf(d, 0.0f);
        crow[jj[fn]] = exp2f(d * cexp);
      }
    }
  }
}

// ---------------------------------------------------------------------------
extern "C" void kernel_launch(void* const* d_in, const int* in_sizes, int n_in,
                              void* d_out, int out_size, void* d_ws, size_t ws_size,
                              hipStream_t stream) {
  const float* A = (const float*)d_in[0];
  const float* B = (const float*)d_in[1];
  float* C = (float*)d_out;

  const size_t bfBytes = (size_t)ND * KD * 2;   // 4 MiB per matrix
  const size_t normBytes = (size_t)ND * 4;      // 32 KiB per norm vector
  char* ws = (char*)d_ws;

  if (ws_size >= 2 * bfBytes + 2 * normBytes) {
    unsigned short* Abf = (unsigned short*)ws;
    unsigned short* Bbf = (unsigned short*)(ws + bfBytes);
    float* asq = (float*)(ws + 2 * bfBytes);
    float* bsq = (float*)(ws + 2 * bfBytes + normBytes);
    hipLaunchKernelGGL(norm_convert_kernel, dim3(2 * ND / 4), dim3(256), 0, stream,
                       A, B, Abf, Bbf, asq, bsq);
    hipLaunchKernelGGL((rbf_gemm_kernel<true>), dim3((ND / BM) * (ND / BN)), dim3(256), 0,
                       stream, (const void*)Abf, (const void*)Bbf, asq, bsq, C);
  } else {
    // Small-workspace fallback: norms only in ws; GEMM converts f32->bf16 inline.
    float* asq = (float*)ws;
    float* bsq = (float*)(ws + normBytes);
    hipLaunchKernelGGL(norm_convert_kernel, dim3(2 * ND / 4), dim3(256), 0, stream,
                       A, B, (unsigned short*)nullptr, (unsigned short*)nullptr, asq, bsq);
    hipLaunchKernelGGL((rbf_gemm_kernel<false>), dim3((ND / BM) * (ND / BN)), dim3(256), 0,
                       stream, (const void*)A, (const void*)B, asq, bsq, C);
  }
}

// Round 2
// 89.195 us; speedup vs baseline: 1.0632x; 1.0632x over previous
//
#include <hip/hip_runtime.h>
#include <hip/hip_bf16.h>
#include <cstdint>
#include <cstddef>

// RBF Gram matrix: K[i,j] = exp(-gamma * max(||a_i||^2 + ||b_j||^2 - 2 a_i.b_j, 0))
// A: [8192,256] f32, B: [8192,256] f32, Out: [8192,8192] f32.
// Prepass: f32 row norms + bf16 copies into d_ws. Main: 128x128 bf16 MFMA GEMM
// with RBF epilogue.
//
// Round-2 changes vs round-1 (which passed at 94.8 us, fabric-bound):
//  * 2-D XCD region mapping: each XCD owns a 16x32-tile region -> per-XCD
//    working set (2 MB B-panel + streaming A) fits the 4 MB XCD L2, so B
//    re-reads stop hitting L3/HBM (was ~500 MB of fabric traffic).
//  * Non-temporal C stores so the 268 MB output stream doesn't evict the
//    L2-resident B panel.

#define GAMMA_F 0.00390625f

typedef __attribute__((ext_vector_type(8))) short short8;   // 8 bf16 (4 VGPRs)
typedef __attribute__((ext_vector_type(4))) float f32x4;    // MFMA acc

constexpr int KD = 256;    // inner dim
constexpr int ND = 8192;   // rows of A and of B (= output dims)
constexpr int BM = 128, BN = 128, BK = 32;

// f32 -> bf16 round-to-nearest-even (no NaN handling needed: inputs are normals)
__device__ __forceinline__ unsigned short f2b(float f) {
  unsigned int u = __float_as_uint(f);
  u += 0x7FFFu + ((u >> 16) & 1u);
  return (unsigned short)(u >> 16);
}

__device__ __forceinline__ void gload_lds16(const void* g, void* l) {
  __builtin_amdgcn_global_load_lds(
      (const __attribute__((address_space(1))) unsigned int*)g,
      (__attribute__((address_space(3))) unsigned int*)l, 16, 0, 0);
}

// ---------------------------------------------------------------------------
// Prepass: row L2-norms (f32, from original f32 data) + optional bf16 convert.
// One wave per row, 4 rows per 256-thread block. 16384 rows total.
// ---------------------------------------------------------------------------
__global__ __launch_bounds__(256) void norm_convert_kernel(
    const float* __restrict__ A, const float* __restrict__ B,
    unsigned short* Abf, unsigned short* Bbf,
    float* __restrict__ asq, float* __restrict__ bsq)
{
  const int lane = threadIdx.x & 63;
  const int row = blockIdx.x * 4 + (threadIdx.x >> 6);
  const float* src = A;
  unsigned short* dst = Abf;
  float* nrm = asq;
  int r = row;
  if (row >= ND) { src = B; dst = Bbf; nrm = bsq; r = row - ND; }

  const float4 v = *(const float4*)(src + (size_t)r * KD + lane * 4);
  float s = v.x * v.x + v.y * v.y + v.z * v.z + v.w * v.w;
  #pragma unroll
  for (int off = 32; off >= 1; off >>= 1) s += __shfl_xor(s, off, 64);

  if (dst) {
    const unsigned int p0 = (unsigned)f2b(v.x) | ((unsigned)f2b(v.y) << 16);
    const unsigned int p1 = (unsigned)f2b(v.z) | ((unsigned)f2b(v.w) << 16);
    *(uint2*)(dst + (size_t)r * KD + lane * 4) = make_uint2(p0, p1);
  }
  if (lane == 0) nrm[r] = s;
}

// ---------------------------------------------------------------------------
// Main GEMM + RBF epilogue.
// 256 threads = 4 waves in a 2x2 grid; each wave owns a 64x64 output sub-tile
// (4x4 fragments of 16x16, acc[4][4] f32x4). BK=32 -> 8 K-steps.
//
// LDS: A-tile [128][32] bf16 (8 KiB) at 0, B-tile at 8192. Linear destination
// for global_load_lds; data is permuted on the GLOBAL-SOURCE side by the
// involution  f(b) = b ^ (((b>>7)&3)<<4)  and ds_read applies the same XOR
// (rule #21: both-sides-or-neither). 2 lanes/bank on fragment reads = free.
// ---------------------------------------------------------------------------
template <bool BF16WS>
__global__ __launch_bounds__(256) void rbf_gemm_kernel(
    const void* __restrict__ Aop, const void* __restrict__ Bop,
    const float* __restrict__ asq, const float* __restrict__ bsq,
    float* __restrict__ C)
{
  __shared__ __align__(16) char smem[16384];
  const int t = threadIdx.x;
  const int lane = t & 63;
  const int wid = t >> 6;
  const int wm = wid >> 1, wn = wid & 1;

  // 2-D XCD region mapping. HW round-robins consecutive blockIdx across the
  // 8 XCDs, so XCD = bid&7 and k = bid>>3 counts this XCD's blocks. Each XCD
  // owns a 16x32-tile region of the 64x64 tile grid (rowband = x>>1,
  // colband = x&1), walked row-major: per-XCD L2 working set = 32 B-tiles
  // (2 MB bf16) + streaming A rows (~fits 4 MB L2). Bijective: 8*512 = 4096.
  const int bid = blockIdx.x;
  const int x = bid & 7;
  const int k = bid >> 3;
  const int tr = ((x >> 1) << 4) + (k >> 5);   // tile row 0..63
  const int tc = ((x & 1) << 5) + (k & 31);    // tile col 0..63
  const int brow = tr << 7;
  const int bcol = tc << 7;

  // Staging coords for thread t: dest byte (per half h) b = h*4096 + t*16.
  // Source linear offset = f(b): row unchanged (= h*64 + t/4), swizzled col.
  const int srow = t >> 2;                                    // 0..63
  const int scolb = (((t & 3) ^ ((t >> 3) & 3)) << 4);        // swizzled col byte

  // Fragment ds_read offsets (kt-invariant; single LDS buffer).
  int aoff[4], boff[4];
  #pragma unroll
  for (int f = 0; f < 4; ++f) {
    const int ra = wm * 64 + f * 16 + (lane & 15);
    aoff[f] = ra * 64 + (((lane >> 4) * 16) ^ (((ra >> 1) & 3) << 4));
    const int rb = wn * 64 + f * 16 + (lane & 15);
    boff[f] = 8192 + rb * 64 + (((lane >> 4) * 16) ^ (((rb >> 1) & 3) << 4));
  }

  f32x4 acc[4][4] = {};

  for (int kt = 0; kt < KD / BK; ++kt) {
    // ---- stage tiles ----
    if constexpr (BF16WS) {
      const char* Ab = (const char*)Aop;
      const char* Bb = (const char*)Bop;
      #pragma unroll
      for (int h = 0; h < 2; ++h) {
        gload_lds16(Ab + (size_t)(brow + h * 64 + srow) * (KD * 2) + kt * (BK * 2) + scolb,
                    smem + h * 4096 + wid * 1024);
        gload_lds16(Bb + (size_t)(bcol + h * 64 + srow) * (KD * 2) + kt * (BK * 2) + scolb,
                    smem + 8192 + h * 4096 + wid * 1024);
      }
    } else {
      // Fallback: reg-stage f32 -> bf16 inline (no big workspace needed).
      const float* Af = (const float*)Aop;
      const float* Bf = (const float*)Bop;
      #pragma unroll
      for (int h = 0; h < 2; ++h) {
        const float* sa = Af + (size_t)(brow + h * 64 + srow) * KD + kt * BK + (scolb >> 1);
        const float4 a0 = *(const float4*)sa;
        const float4 a1 = *(const float4*)(sa + 4);
        const uint4 pa = make_uint4(
            (unsigned)f2b(a0.x) | ((unsigned)f2b(a0.y) << 16),
            (unsigned)f2b(a0.z) | ((unsigned)f2b(a0.w) << 16),
            (unsigned)f2b(a1.x) | ((unsigned)f2b(a1.y) << 16),
            (unsigned)f2b(a1.z) | ((unsigned)f2b(a1.w) << 16));
        *(uint4*)(smem + h * 4096 + t * 16) = pa;
        const float* sb = Bf + (size_t)(bcol + h * 64 + srow) * KD + kt * BK + (scolb >> 1);
        const float4 b0 = *(const float4*)sb;
        const float4 b1 = *(const float4*)(sb + 4);
        const uint4 pb = make_uint4(
            (unsigned)f2b(b0.x) | ((unsigned)f2b(b0.y) << 16),
            (unsigned)f2b(b0.z) | ((unsigned)f2b(b0.w) << 16),
            (unsigned)f2b(b1.x) | ((unsigned)f2b(b1.y) << 16),
            (unsigned)f2b(b1.z) | ((unsigned)f2b(b1.w) << 16));
        *(uint4*)(smem + 8192 + h * 4096 + t * 16) = pb;
      }
    }
    __syncthreads();   // compiler drains vmcnt/lgkmcnt before s_barrier

    // ---- compute ----
    short8 af[4], bfv[4];
    #pragma unroll
    for (int f = 0; f < 4; ++f) {
      af[f]  = *(const short8*)(smem + aoff[f]);
      bfv[f] = *(const short8*)(smem + boff[f]);
    }
    #pragma unroll
    for (int fm = 0; fm < 4; ++fm)
      #pragma unroll
      for (int fn = 0; fn < 4; ++fn)
        acc[fm][fn] = __builtin_amdgcn_mfma_f32_16x16x32_bf16(
            af[fm], bfv[fn], acc[fm][fn], 0, 0, 0);
    __syncthreads();   // all reads done before next stage overwrites LDS
  }

  // ---- epilogue: K = exp2( (asq+bsq-2*dot) * (-gamma*log2e) ) ----
  // C/D layout (m89): col = lane&15, row = (lane>>4)*4 + reg.
  // Non-temporal stores: C is write-once streaming data; keep it out of L2
  // so the resident B panel survives.
  const float cexp = -GAMMA_F * 1.44269504088896340736f;
  float bn[4];
  int jj[4];
  #pragma unroll
  for (int fn = 0; fn < 4; ++fn) {
    jj[fn] = bcol + wn * 64 + fn * 16 + (lane & 15);
    bn[fn] = bsq[jj[fn]];
  }
  #pragma unroll
  for (int fm = 0; fm < 4; ++fm) {
    const int ib = brow + wm * 64 + fm * 16 + ((lane >> 4) << 2);
    #pragma unroll
    for (int r = 0; r < 4; ++r) {
      const float an = asq[ib + r];
      float* crow = C + (size_t)(ib + r) * ND;
      #pragma unroll
      for (int fn = 0; fn < 4; ++fn) {
        float d = an + bn[fn] - 2.0f * acc[fm][fn][r];
        d = fmaxf(d, 0.0f);
        __builtin_nontemporal_store(exp2f(d * cexp), &crow[jj[fn]]);
      }
    }
  }
}

// ---------------------------------------------------------------------------
extern "C" void kernel_launch(void* const* d_in, const int* in_sizes, int n_in,
                              void* d_out, int out_size, void* d_ws, size_t ws_size,
                              hipStream_t stream) {
  const float* A = (const float*)d_in[0];
  const float* B = (const float*)d_in[1];
  float* C = (float*)d_out;

  const size_t bfBytes = (size_t)ND * KD * 2;   // 4 MiB per matrix
  const size_t normBytes = (size_t)ND * 4;      // 32 KiB per norm vector
  char* ws = (char*)d_ws;

  if (ws_size >= 2 * bfBytes + 2 * normBytes) {
    unsigned short* Abf = (unsigned short*)ws;
    unsigned short* Bbf = (unsigned short*)(ws + bfBytes);
    float* asq = (float*)(ws + 2 * bfBytes);
    float* bsq = (float*)(ws + 2 * bfBytes + normBytes);
    hipLaunchKernelGGL(norm_convert_kernel, dim3(2 * ND / 4), dim3(256), 0, stream,
                       A, B, Abf, Bbf, asq, bsq);
    hipLaunchKernelGGL((rbf_gemm_kernel<true>), dim3((ND / BM) * (ND / BN)), dim3(256), 0,
                       stream, (const void*)Abf, (const void*)Bbf, asq, bsq, C);
  } else {
    // Small-workspace fallback: norms only in ws; GEMM converts f32->bf16 inline.
    float* asq = (float*)ws;
    float* bsq = (float*)(ws + normBytes);
    hipLaunchKernelGGL(norm_convert_kernel, dim3(2 * ND / 4), dim3(256), 0, stream,
                       A, B, (unsigned short*)nullptr, (unsigned short*)nullptr, asq, bsq);
    hipLaunchKernelGGL((rbf_gemm_kernel<false>), dim3((ND / BM) * (ND / BN)), dim3(256), 0,
                       stream, (const void*)A, (const void*)B, asq, bsq, C);
  }
}